// Round 2
// baseline (844.047 us; speedup 1.0000x reference)
//
#include <hip/hip_runtime.h>
#include <hip/hip_fp16.h>

#define NU 100000
#define NI 50000
#define NB 1000
#define NN 151000          // total nodes
#define NE 4800000
#define KDIM 448

#define BROW_BITS 9
#define BROWS 512                       // rows per bucket
#define NBK ((NN + BROWS - 1) / BROWS)  // 295 buckets

// ================= Phase A: bucket histogram (LDS-aggregated) =================
#define HIST_EPT 16
__global__ __launch_bounds__(256) void bucket_hist(const int* __restrict__ erow,
                                                   int* __restrict__ bcnt) {
  __shared__ int lh[NBK];
  for (int i = threadIdx.x; i < NBK; i += 256) lh[i] = 0;
  __syncthreads();
  int base = blockIdx.x * (256 * HIST_EPT) + threadIdx.x;
#pragma unroll
  for (int j = 0; j < HIST_EPT; ++j) {
    int e = base + j * 256;
    if (e < NE) atomicAdd(&lh[erow[e] >> BROW_BITS], 1);
  }
  __syncthreads();
  for (int i = threadIdx.x; i < NBK; i += 256) {
    int c = lh[i];
    if (c) atomicAdd(&bcnt[i], c);
  }
}

// ================= Phase B: scan 295 bucket counts (single block) =================
__global__ __launch_bounds__(256) void bucket_scan(const int* __restrict__ bcnt,
                                                   int* __restrict__ bstart,
                                                   int* __restrict__ rp) {
  __shared__ int sh[256];
  int tid = threadIdx.x;
  int v[2];
  int s = 0;
#pragma unroll
  for (int j = 0; j < 2; ++j) {
    int i = tid * 2 + j;
    v[j] = (i < NBK) ? bcnt[i] : 0;
    s += v[j];
  }
  sh[tid] = s;
  __syncthreads();
  for (int off = 1; off < 256; off <<= 1) {
    int t = (tid >= off) ? sh[tid - off] : 0;
    __syncthreads();
    sh[tid] += t;
    __syncthreads();
  }
  int run = sh[tid] - s;  // exclusive
#pragma unroll
  for (int j = 0; j < 2; ++j) {
    int i = tid * 2 + j;
    if (i < NBK) bstart[i] = run;
    run += v[j];
  }
  if (tid == 255) {
    bstart[NBK] = NE;
    rp[NN] = NE;
  }
}

// ================= Phase C: scatter edges into bucket order =================
// key packs (row&511)<<18 | col  (col < 151000 < 2^18, key < 2^27)
#define SC_EPT 32
__global__ __launch_bounds__(256) void bucket_scatter(
    const int* __restrict__ erow, const int* __restrict__ ecol,
    const float* __restrict__ eval, const int* __restrict__ bstart,
    int* __restrict__ gfill, int2* __restrict__ cvtmp) {
  __shared__ int lcnt[NBK];
  __shared__ int lbase[NBK];
  __shared__ unsigned short lrank[256 * SC_EPT];  // 16 KB
  for (int i = threadIdx.x; i < NBK; i += 256) lcnt[i] = 0;
  __syncthreads();
  int base = blockIdx.x * (256 * SC_EPT) + threadIdx.x;
  int rv[SC_EPT];  // register cache of erow (fully unrolled -> VGPRs)
  // phase 1: per-(block,bucket) ranks
#pragma unroll
  for (int j = 0; j < SC_EPT; ++j) {
    int e = base + j * 256;
    if (e < NE) {
      int r = erow[e];
      rv[j] = r;
      lrank[j * 256 + threadIdx.x] = (unsigned short)atomicAdd(&lcnt[r >> BROW_BITS], 1);
    } else {
      rv[j] = -1;
    }
  }
  __syncthreads();
  // reserve global ranges (one atomic per non-empty bucket per block)
  for (int i = threadIdx.x; i < NBK; i += 256) {
    int c = lcnt[i];
    lbase[i] = c ? atomicAdd(&gfill[i], c) : 0;
  }
  __syncthreads();
  // phase 2: packed 8B writes; ~28 consecutive edges per bucket per block
#pragma unroll
  for (int j = 0; j < SC_EPT; ++j) {
    int e = base + j * 256;
    if (e < NE) {
      int r = rv[j];
      int c = ecol[e];
      float v = eval[e];
      int bk = r >> BROW_BITS;
      int key = ((r & (BROWS - 1)) << 18) | c;
      int p = bstart[bk] + lbase[bk] + lrank[j * 256 + threadIdx.x];
      cvtmp[p] = make_int2(key, __float_as_int(v));
    }
  }
}

// ================= Phase D: per-bucket CSR finalize + rp =================
__global__ __launch_bounds__(256) void csr_finalize(
    const int* __restrict__ bstart, const int2* __restrict__ cvtmp,
    int* __restrict__ rp, int2* __restrict__ cv) {
  __shared__ int rcnt[BROWS];
  __shared__ int rex[BROWS];
  __shared__ int ssh[256];
  int b = blockIdx.x;
  int s0 = bstart[b], s1 = bstart[b + 1];
  int tid = threadIdx.x;
  rcnt[tid] = 0;
  rcnt[tid + 256] = 0;
  __syncthreads();
  for (int j = s0 + tid; j < s1; j += 256) atomicAdd(&rcnt[cvtmp[j].x >> 18], 1);
  __syncthreads();
  int v0 = rcnt[2 * tid], v1 = rcnt[2 * tid + 1];
  int tsum = v0 + v1;
  ssh[tid] = tsum;
  __syncthreads();
  for (int off = 1; off < 256; off <<= 1) {
    int t = (tid >= off) ? ssh[tid - off] : 0;
    __syncthreads();
    ssh[tid] += t;
    __syncthreads();
  }
  int excl = ssh[tid] - tsum;
  rex[2 * tid] = excl;
  rex[2 * tid + 1] = excl + v0;
  int row = b * BROWS + 2 * tid;
  if (row < NN) rp[row] = s0 + excl;
  if (row + 1 < NN) rp[row + 1] = s0 + excl + v0;
  rcnt[2 * tid] = 0;
  rcnt[2 * tid + 1] = 0;
  __syncthreads();
  for (int j = s0 + tid; j < s1; j += 256) {
    int2 kv = cvtmp[j];
    int r = kv.x >> 18;
    int c = kv.x & 0x3FFFF;
    int rk = atomicAdd(&rcnt[r], 1);
    cv[s0 + rex[r] + rk] = make_int2(c, kv.y);
  }
}

// ======= fusion GEMM: [NI x 448] @ W^T + bias + leaky; writes fp32 acc-seed + fp16 x =======
__global__ __launch_bounds__(256) void fusion_kernel(
    const float* __restrict__ id_emb, const float* __restrict__ content,
    const float* __restrict__ W, const float* __restrict__ bias,
    __half* __restrict__ xh, float* __restrict__ out) {
  __shared__ float As[16][68];
  __shared__ float Ws[16][68];
  int tid = threadIdx.x;
  int tx = tid & 15;
  int ty = tid >> 4;
  int itemBase = blockIdx.x * 64;
  float acc[4][4] = {};

  int it = tid >> 2;
  int kq = (tid & 3) * 4;

  for (int kb = 0; kb < KDIM; kb += 16) {
    int k = kb + kq;
    int item = itemBase + it;
    int itemc = item < NI ? item : NI - 1;
    float4 a;
    if (k < 64)
      a = *(const float4*)&id_emb[(size_t)itemc * 64 + k];
    else
      a = *(const float4*)&content[(size_t)itemc * 384 + (k - 64)];
    As[kq + 0][it] = a.x; As[kq + 1][it] = a.y; As[kq + 2][it] = a.z; As[kq + 3][it] = a.w;
    float4 w = *(const float4*)&W[(size_t)it * KDIM + k];
    Ws[kq + 0][it] = w.x; Ws[kq + 1][it] = w.y; Ws[kq + 2][it] = w.z; Ws[kq + 3][it] = w.w;
    __syncthreads();
#pragma unroll
    for (int kk = 0; kk < 16; ++kk) {
      float4 af = *(float4*)&As[kk][ty * 4];
      float4 wf = *(float4*)&Ws[kk][tx * 4];
      float av[4] = {af.x, af.y, af.z, af.w};
      float wv[4] = {wf.x, wf.y, wf.z, wf.w};
#pragma unroll
      for (int m = 0; m < 4; ++m)
#pragma unroll
        for (int n = 0; n < 4; ++n) acc[m][n] += av[m] * wv[n];
    }
    __syncthreads();
  }

  int d0 = tx * 4;
  float4 bb = *(const float4*)&bias[d0];
#pragma unroll
  for (int m = 0; m < 4; ++m) {
    int item = itemBase + ty * 4 + m;
    if (item >= NI) continue;
    float4 o;
    float t;
    t = acc[m][0] + bb.x; o.x = t >= 0.f ? t : 0.01f * t;
    t = acc[m][1] + bb.y; o.y = t >= 0.f ? t : 0.01f * t;
    t = acc[m][2] + bb.z; o.z = t >= 0.f ? t : 0.01f * t;
    t = acc[m][3] + bb.w; o.w = t >= 0.f ? t : 0.01f * t;
    size_t ofs = (size_t)(NU + item) * 64 + d0;
    *(float4*)&out[ofs] = o;                       // fp32 acc seed
    *(__half2*)&xh[ofs] = __floats2half2_rn(o.x, o.y);
    *(__half2*)&xh[ofs + 2] = __floats2half2_rn(o.z, o.w);
  }
}

// ======= seed: user/brand -> acc seed + fp16 x; user/item passthrough copies =======
#define UN (NU * 64)     // 6400000
#define BN (NB * 64)     // 64000
#define IEL (NI * 64)    // 3200000
__global__ __launch_bounds__(256) void seed_kernel(
    const float* __restrict__ user_emb, const float* __restrict__ brand,
    const float* __restrict__ item_id, __half* __restrict__ xh,
    float* __restrict__ out) {
  int idx = (blockIdx.x * 256 + threadIdx.x) * 4;
  if (idx < UN) {
    float4 f = *(const float4*)&user_emb[idx];
    *(float4*)&out[idx] = f;                         // acc seed
    *(float4*)&out[(size_t)NN * 64 + idx] = f;       // user passthrough
    *(__half2*)&xh[idx] = __floats2half2_rn(f.x, f.y);
    *(__half2*)&xh[idx + 2] = __floats2half2_rn(f.z, f.w);
  } else if (idx < UN + BN) {
    int k = idx - UN;
    float4 f = *(const float4*)&brand[k];
    int o = (NU + NI) * 64 + k;
    *(float4*)&out[o] = f;                           // acc seed
    *(__half2*)&xh[o] = __floats2half2_rn(f.x, f.y);
    *(__half2*)&xh[o + 2] = __floats2half2_rn(f.z, f.w);
  } else if (idx < UN + BN + IEL) {
    int k = idx - (UN + BN);
    float4 f = *(const float4*)&item_id[k];
    *(float4*)&out[(size_t)(NN + NU) * 64 + k] = f;  // item_id passthrough
  }
}

// nontemporal 8B load of a cv entry (single-use stream per pass; keep x in L2)
__device__ __forceinline__ int2 nt_cv(const int2* p) {
  long long t = __builtin_nontemporal_load((const long long*)p);
  int2 r;
  r.x = (int)(unsigned int)t;
  r.y = (int)(t >> 32);
  return r;
}

// ======= SpMM: 1 wave/row, 4x16-lane groups, predicated 8-deep gather (no tail) =======
// Avg degree ~32 -> most rows complete in ONE iteration with 8 gathers in flight
// per group. OOB edges clamp to end-1 (same line, L1 hit) with v=0.
template <bool FINAL>
__global__ __launch_bounds__(256, 8) void spmm_kernel(
    const int* __restrict__ rp, const int2* __restrict__ cv,
    const __half* __restrict__ x, __half* __restrict__ y,
    float* __restrict__ acc) {
  int wid = blockIdx.x * 4 + (threadIdx.x >> 6);
  if (wid >= NN) return;
  int lane = threadIdx.x & 63;
  int grp = lane >> 4;          // 0..3: edge group (stride-4 edge walk)
  int d0 = (lane & 15) << 2;    // 4 dims owned per lane
  const __half* __restrict__ xb = x + d0;
  int beg = rp[wid], end = rp[wid + 1];
  int e1 = end - 1;
  float a0 = 0.f, a1 = 0.f, a2 = 0.f, a3 = 0.f;
  float b0 = 0.f, b1 = 0.f, b2 = 0.f, b3 = 0.f;
  for (int j0 = beg + grp; j0 < end; j0 += 32) {
    int j1 = j0 + 4, j2 = j0 + 8, j3 = j0 + 12;
    int j4 = j0 + 16, j5 = j0 + 20, j6 = j0 + 24, j7 = j0 + 28;
    // 8 independent cv loads (nt: streaming)
    int2 p0 = nt_cv(cv + j0);            // k=0 always in range
    int2 p1 = nt_cv(cv + min(j1, e1));
    int2 p2 = nt_cv(cv + min(j2, e1));
    int2 p3 = nt_cv(cv + min(j3, e1));
    int2 p4 = nt_cv(cv + min(j4, e1));
    int2 p5 = nt_cv(cv + min(j5, e1));
    int2 p6 = nt_cv(cv + min(j6, e1));
    int2 p7 = nt_cv(cv + min(j7, e1));
    // 8 independent 8B gathers (128B/line per 16-lane group)
    uint2 h0 = *(const uint2*)(xb + (p0.x << 6));
    uint2 h1 = *(const uint2*)(xb + (p1.x << 6));
    uint2 h2 = *(const uint2*)(xb + (p2.x << 6));
    uint2 h3 = *(const uint2*)(xb + (p3.x << 6));
    uint2 h4 = *(const uint2*)(xb + (p4.x << 6));
    uint2 h5 = *(const uint2*)(xb + (p5.x << 6));
    uint2 h6 = *(const uint2*)(xb + (p6.x << 6));
    uint2 h7 = *(const uint2*)(xb + (p7.x << 6));
    float v0 = __int_as_float(p0.y);
    float v1 = (j1 < end) ? __int_as_float(p1.y) : 0.f;
    float v2 = (j2 < end) ? __int_as_float(p2.y) : 0.f;
    float v3 = (j3 < end) ? __int_as_float(p3.y) : 0.f;
    float v4 = (j4 < end) ? __int_as_float(p4.y) : 0.f;
    float v5 = (j5 < end) ? __int_as_float(p5.y) : 0.f;
    float v6 = (j6 < end) ? __int_as_float(p6.y) : 0.f;
    float v7 = (j7 < end) ? __int_as_float(p7.y) : 0.f;
    float2 f;
    f = __half22float2(*(__half2*)&h0.x); a0 += v0 * f.x; a1 += v0 * f.y;
    f = __half22float2(*(__half2*)&h0.y); a2 += v0 * f.x; a3 += v0 * f.y;
    f = __half22float2(*(__half2*)&h1.x); b0 += v1 * f.x; b1 += v1 * f.y;
    f = __half22float2(*(__half2*)&h1.y); b2 += v1 * f.x; b3 += v1 * f.y;
    f = __half22float2(*(__half2*)&h2.x); a0 += v2 * f.x; a1 += v2 * f.y;
    f = __half22float2(*(__half2*)&h2.y); a2 += v2 * f.x; a3 += v2 * f.y;
    f = __half22float2(*(__half2*)&h3.x); b0 += v3 * f.x; b1 += v3 * f.y;
    f = __half22float2(*(__half2*)&h3.y); b2 += v3 * f.x; b3 += v3 * f.y;
    f = __half22float2(*(__half2*)&h4.x); a0 += v4 * f.x; a1 += v4 * f.y;
    f = __half22float2(*(__half2*)&h4.y); a2 += v4 * f.x; a3 += v4 * f.y;
    f = __half22float2(*(__half2*)&h5.x); b0 += v5 * f.x; b1 += v5 * f.y;
    f = __half22float2(*(__half2*)&h5.y); b2 += v5 * f.x; b3 += v5 * f.y;
    f = __half22float2(*(__half2*)&h6.x); a0 += v6 * f.x; a1 += v6 * f.y;
    f = __half22float2(*(__half2*)&h6.y); a2 += v6 * f.x; a3 += v6 * f.y;
    f = __half22float2(*(__half2*)&h7.x); b0 += v7 * f.x; b1 += v7 * f.y;
    f = __half22float2(*(__half2*)&h7.y); b2 += v7 * f.x; b3 += v7 * f.y;
  }
  a0 += b0; a1 += b1; a2 += b2; a3 += b3;
  // reduce the 4 groups (epilogue only)
  a0 += __shfl_xor(a0, 16); a1 += __shfl_xor(a1, 16);
  a2 += __shfl_xor(a2, 16); a3 += __shfl_xor(a3, 16);
  a0 += __shfl_xor(a0, 32); a1 += __shfl_xor(a1, 32);
  a2 += __shfl_xor(a2, 32); a3 += __shfl_xor(a3, 32);
  if (lane < 16) {
    int o = (wid << 6) | d0;
    if (FINAL) {
      float4 t = *(const float4*)&acc[o];
      t.x = (t.x + a0) * 0.25f;
      t.y = (t.y + a1) * 0.25f;
      t.z = (t.z + a2) * 0.25f;
      t.w = (t.w + a3) * 0.25f;
      *(float4*)&acc[o] = t;
    } else {
      *(__half2*)&y[o] = __floats2half2_rn(a0, a1);
      *(__half2*)&y[o + 2] = __floats2half2_rn(a2, a3);
      float4 t = *(const float4*)&acc[o];
      t.x += a0; t.y += a1; t.z += a2; t.w += a3;
      *(float4*)&acc[o] = t;
    }
  }
}

extern "C" void kernel_launch(void* const* d_in, const int* in_sizes, int n_in,
                              void* d_out, int out_size, void* d_ws, size_t ws_size,
                              hipStream_t stream) {
  const int*   edge_row = (const int*)d_in[0];
  const int*   edge_col = (const int*)d_in[1];
  const float* edge_val = (const float*)d_in[2];
  const float* user_emb = (const float*)d_in[3];
  const float* item_id  = (const float*)d_in[4];
  const float* brand    = (const float*)d_in[5];
  const float* content  = (const float*)d_in[6];
  const float* W        = (const float*)d_in[7];
  const float* bias     = (const float*)d_in[8];
  float* out = (float*)d_out;

  char* ws = (char*)d_ws;
  size_t off = 0;
  auto alloc = [&](size_t bytes) -> void* {
    void* p = ws + off;
    off += (bytes + 255) & ~(size_t)255;
    return p;
  };
  __half* xh0   = (__half*)alloc((size_t)NN * 64 * 2);  // 19.33 MB
  __half* xh1   = (__half*)alloc((size_t)NN * 64 * 2);  // 19.33 MB
  int2*   cvtmp = (int2*)alloc((size_t)NE * 8);         // 38.4 MB
  int2*   cv    = (int2*)alloc((size_t)NE * 8);         // 38.4 MB
  int*    rp    = (int*)alloc((size_t)(NN + 1) * 4);
  int*    bcnt  = (int*)alloc((NBK + 1) * 4);
  int*    bstart= (int*)alloc((NBK + 1) * 4);
  int*    gfill = (int*)alloc((NBK + 1) * 4);
  if (off > ws_size) return;

  // --- build CSR via two-level counting sort ---
  // bcnt/bstart/gfill are contiguous in the workspace: one memset covers all
  // (bstart is fully overwritten by bucket_scan before use).
  hipMemsetAsync(bcnt, 0, (size_t)((char*)gfill - (char*)bcnt) + (NBK + 1) * 4,
                 stream);
  const int histBlocks = (NE + 256 * HIST_EPT - 1) / (256 * HIST_EPT);
  bucket_hist<<<histBlocks, 256, 0, stream>>>(edge_row, bcnt);
  bucket_scan<<<1, 256, 0, stream>>>(bcnt, bstart, rp);
  const int scBlocks = (NE + 256 * SC_EPT - 1) / (256 * SC_EPT);
  bucket_scatter<<<scBlocks, 256, 0, stream>>>(edge_row, edge_col, edge_val,
                                               bstart, gfill, cvtmp);
  csr_finalize<<<NBK, 256, 0, stream>>>(bstart, cvtmp, rp, cv);

  // --- ego assembly, acc seeding, fp16 conversion, passthrough (fused) ---
  fusion_kernel<<<(NI + 63) / 64, 256, 0, stream>>>(item_id, content, W, bias,
                                                    xh0, out);
  const int seedTot = UN + BN + IEL;  // 9,664,000 floats
  seed_kernel<<<(seedTot / 4 + 255) / 256, 256, 0, stream>>>(user_emb, brand,
                                                             item_id, xh0, out);

  // --- 3 propagation layers ---
  const int spmmGrid = (NN + 3) / 4;
  spmm_kernel<false><<<spmmGrid, 256, 0, stream>>>(rp, cv, xh0, xh1, out);
  spmm_kernel<false><<<spmmGrid, 256, 0, stream>>>(rp, cv, xh1, xh0, out);
  spmm_kernel<true><<<spmmGrid, 256, 0, stream>>>(rp, cv, xh0, xh1, out);
}

// Round 3
// 722.309 us; speedup vs baseline: 1.1685x; 1.1685x over previous
//
#include <hip/hip_runtime.h>
#include <hip/hip_fp16.h>

#define NU 100000
#define NI 50000
#define NB 1000
#define NN 151000          // total nodes
#define NE 4800000
#define KDIM 448

#define BROW_BITS 9
#define BROWS 512                       // rows per bucket
#define NBK ((NN + BROWS - 1) / BROWS)  // 295 buckets

typedef float v2f __attribute__((ext_vector_type(2)));

// pack 4 floats -> 4x fp8 e4m3 (OCP on gfx950) in one dword
__device__ __forceinline__ unsigned int pk_fp8x4(float a, float b, float c, float d) {
  int r = 0;
  r = __builtin_amdgcn_cvt_pk_fp8_f32(a, b, r, false);  // low 16
  r = __builtin_amdgcn_cvt_pk_fp8_f32(c, d, r, true);   // high 16
  return (unsigned int)r;
}

// ================= Phase A: bucket histogram (LDS-aggregated) =================
#define HIST_EPT 16
__global__ __launch_bounds__(256) void bucket_hist(const int* __restrict__ erow,
                                                   int* __restrict__ bcnt) {
  __shared__ int lh[NBK];
  for (int i = threadIdx.x; i < NBK; i += 256) lh[i] = 0;
  __syncthreads();
  int base = blockIdx.x * (256 * HIST_EPT) + threadIdx.x;
#pragma unroll
  for (int j = 0; j < HIST_EPT; ++j) {
    int e = base + j * 256;
    if (e < NE) atomicAdd(&lh[erow[e] >> BROW_BITS], 1);
  }
  __syncthreads();
  for (int i = threadIdx.x; i < NBK; i += 256) {
    int c = lh[i];
    if (c) atomicAdd(&bcnt[i], c);
  }
}

// ================= Phase B: scan 295 bucket counts (single block) =================
__global__ __launch_bounds__(256) void bucket_scan(const int* __restrict__ bcnt,
                                                   int* __restrict__ bstart,
                                                   int* __restrict__ rp) {
  __shared__ int sh[256];
  int tid = threadIdx.x;
  int v[2];
  int s = 0;
#pragma unroll
  for (int j = 0; j < 2; ++j) {
    int i = tid * 2 + j;
    v[j] = (i < NBK) ? bcnt[i] : 0;
    s += v[j];
  }
  sh[tid] = s;
  __syncthreads();
  for (int off = 1; off < 256; off <<= 1) {
    int t = (tid >= off) ? sh[tid - off] : 0;
    __syncthreads();
    sh[tid] += t;
    __syncthreads();
  }
  int run = sh[tid] - s;  // exclusive
#pragma unroll
  for (int j = 0; j < 2; ++j) {
    int i = tid * 2 + j;
    if (i < NBK) bstart[i] = run;
    run += v[j];
  }
  if (tid == 255) {
    bstart[NBK] = NE;
    rp[NN] = NE;
  }
}

// ================= Phase C: scatter edges into bucket order =================
// key packs (row&511)<<18 | col  (col < 151000 < 2^18, key < 2^27)
#define SC_EPT 32
__global__ __launch_bounds__(256) void bucket_scatter(
    const int* __restrict__ erow, const int* __restrict__ ecol,
    const float* __restrict__ eval, const int* __restrict__ bstart,
    int* __restrict__ gfill, int2* __restrict__ cvtmp) {
  __shared__ int lcnt[NBK];
  __shared__ int lbase[NBK];
  __shared__ unsigned short lrank[256 * SC_EPT];  // 16 KB
  for (int i = threadIdx.x; i < NBK; i += 256) lcnt[i] = 0;
  __syncthreads();
  int base = blockIdx.x * (256 * SC_EPT) + threadIdx.x;
  int rv[SC_EPT];  // register cache of erow (fully unrolled -> VGPRs)
  // phase 1: per-(block,bucket) ranks
#pragma unroll
  for (int j = 0; j < SC_EPT; ++j) {
    int e = base + j * 256;
    if (e < NE) {
      int r = erow[e];
      rv[j] = r;
      lrank[j * 256 + threadIdx.x] = (unsigned short)atomicAdd(&lcnt[r >> BROW_BITS], 1);
    } else {
      rv[j] = -1;
    }
  }
  __syncthreads();
  // reserve global ranges (one atomic per non-empty bucket per block)
  for (int i = threadIdx.x; i < NBK; i += 256) {
    int c = lcnt[i];
    lbase[i] = c ? atomicAdd(&gfill[i], c) : 0;
  }
  __syncthreads();
  // phase 2: packed 8B writes; ~28 consecutive edges per bucket per block
#pragma unroll
  for (int j = 0; j < SC_EPT; ++j) {
    int e = base + j * 256;
    if (e < NE) {
      int r = rv[j];
      int c = ecol[e];
      float v = eval[e];
      int bk = r >> BROW_BITS;
      int key = ((r & (BROWS - 1)) << 18) | c;
      int p = bstart[bk] + lbase[bk] + lrank[j * 256 + threadIdx.x];
      cvtmp[p] = make_int2(key, __float_as_int(v));
    }
  }
}

// ================= Phase D: per-bucket CSR finalize + rp =================
__global__ __launch_bounds__(256) void csr_finalize(
    const int* __restrict__ bstart, const int2* __restrict__ cvtmp,
    int* __restrict__ rp, int2* __restrict__ cv) {
  __shared__ int rcnt[BROWS];
  __shared__ int rex[BROWS];
  __shared__ int ssh[256];
  int b = blockIdx.x;
  int s0 = bstart[b], s1 = bstart[b + 1];
  int tid = threadIdx.x;
  rcnt[tid] = 0;
  rcnt[tid + 256] = 0;
  __syncthreads();
  for (int j = s0 + tid; j < s1; j += 256) atomicAdd(&rcnt[cvtmp[j].x >> 18], 1);
  __syncthreads();
  int v0 = rcnt[2 * tid], v1 = rcnt[2 * tid + 1];
  int tsum = v0 + v1;
  ssh[tid] = tsum;
  __syncthreads();
  for (int off = 1; off < 256; off <<= 1) {
    int t = (tid >= off) ? ssh[tid - off] : 0;
    __syncthreads();
    ssh[tid] += t;
    __syncthreads();
  }
  int excl = ssh[tid] - tsum;
  rex[2 * tid] = excl;
  rex[2 * tid + 1] = excl + v0;
  int row = b * BROWS + 2 * tid;
  if (row < NN) rp[row] = s0 + excl;
  if (row + 1 < NN) rp[row + 1] = s0 + excl + v0;
  rcnt[2 * tid] = 0;
  rcnt[2 * tid + 1] = 0;
  __syncthreads();
  for (int j = s0 + tid; j < s1; j += 256) {
    int2 kv = cvtmp[j];
    int r = kv.x >> 18;
    int c = kv.x & 0x3FFFF;
    int rk = atomicAdd(&rcnt[r], 1);
    cv[s0 + rex[r] + rk] = make_int2(c, kv.y);
  }
}

// ======= fusion GEMM: [NI x 448] @ W^T + bias + leaky; writes fp32 acc-seed + fp8 x =======
__global__ __launch_bounds__(256) void fusion_kernel(
    const float* __restrict__ id_emb, const float* __restrict__ content,
    const float* __restrict__ W, const float* __restrict__ bias,
    unsigned char* __restrict__ x8, float* __restrict__ out) {
  __shared__ float As[16][68];
  __shared__ float Ws[16][68];
  int tid = threadIdx.x;
  int tx = tid & 15;
  int ty = tid >> 4;
  int itemBase = blockIdx.x * 64;
  float acc[4][4] = {};

  int it = tid >> 2;
  int kq = (tid & 3) * 4;

  for (int kb = 0; kb < KDIM; kb += 16) {
    int k = kb + kq;
    int item = itemBase + it;
    int itemc = item < NI ? item : NI - 1;
    float4 a;
    if (k < 64)
      a = *(const float4*)&id_emb[(size_t)itemc * 64 + k];
    else
      a = *(const float4*)&content[(size_t)itemc * 384 + (k - 64)];
    As[kq + 0][it] = a.x; As[kq + 1][it] = a.y; As[kq + 2][it] = a.z; As[kq + 3][it] = a.w;
    float4 w = *(const float4*)&W[(size_t)it * KDIM + k];
    Ws[kq + 0][it] = w.x; Ws[kq + 1][it] = w.y; Ws[kq + 2][it] = w.z; Ws[kq + 3][it] = w.w;
    __syncthreads();
#pragma unroll
    for (int kk = 0; kk < 16; ++kk) {
      float4 af = *(float4*)&As[kk][ty * 4];
      float4 wf = *(float4*)&Ws[kk][tx * 4];
      float av[4] = {af.x, af.y, af.z, af.w};
      float wv[4] = {wf.x, wf.y, wf.z, wf.w};
#pragma unroll
      for (int m = 0; m < 4; ++m)
#pragma unroll
        for (int n = 0; n < 4; ++n) acc[m][n] += av[m] * wv[n];
    }
    __syncthreads();
  }

  int d0 = tx * 4;
  float4 bb = *(const float4*)&bias[d0];
#pragma unroll
  for (int m = 0; m < 4; ++m) {
    int item = itemBase + ty * 4 + m;
    if (item >= NI) continue;
    float4 o;
    float t;
    t = acc[m][0] + bb.x; o.x = t >= 0.f ? t : 0.01f * t;
    t = acc[m][1] + bb.y; o.y = t >= 0.f ? t : 0.01f * t;
    t = acc[m][2] + bb.z; o.z = t >= 0.f ? t : 0.01f * t;
    t = acc[m][3] + bb.w; o.w = t >= 0.f ? t : 0.01f * t;
    size_t ofs = (size_t)(NU + item) * 64 + d0;
    *(float4*)&out[ofs] = o;                       // fp32 acc seed
    *(unsigned int*)&x8[ofs] = pk_fp8x4(o.x, o.y, o.z, o.w);
  }
}

// ======= seed: user/brand -> acc seed + fp8 x; user/item passthrough copies =======
#define UN (NU * 64)     // 6400000
#define BN (NB * 64)     // 64000
#define IEL (NI * 64)    // 3200000
__global__ __launch_bounds__(256) void seed_kernel(
    const float* __restrict__ user_emb, const float* __restrict__ brand,
    const float* __restrict__ item_id, unsigned char* __restrict__ x8,
    float* __restrict__ out) {
  int idx = (blockIdx.x * 256 + threadIdx.x) * 4;
  if (idx < UN) {
    float4 f = *(const float4*)&user_emb[idx];
    *(float4*)&out[idx] = f;                         // acc seed
    *(float4*)&out[(size_t)NN * 64 + idx] = f;       // user passthrough
    *(unsigned int*)&x8[idx] = pk_fp8x4(f.x, f.y, f.z, f.w);
  } else if (idx < UN + BN) {
    int k = idx - UN;
    float4 f = *(const float4*)&brand[k];
    int o = (NU + NI) * 64 + k;
    *(float4*)&out[o] = f;                           // acc seed
    *(unsigned int*)&x8[o] = pk_fp8x4(f.x, f.y, f.z, f.w);
  } else if (idx < UN + BN + IEL) {
    int k = idx - (UN + BN);
    float4 f = *(const float4*)&item_id[k];
    *(float4*)&out[(size_t)(NN + NU) * 64 + k] = f;  // item_id passthrough
  }
}

// ======= SpMM: 1 wave/row, 4x16-lane groups, 4B fp8 gathers (64B/edge) =======
// R1 structure (known-good); only the x dtype changed fp16 -> fp8 e4m3.
template <bool FINAL>
__global__ __launch_bounds__(256) void spmm_kernel(
    const int* __restrict__ rp, const int2* __restrict__ cv,
    const unsigned char* __restrict__ x, unsigned char* __restrict__ y,
    float* __restrict__ acc) {
  int wid = blockIdx.x * 4 + (threadIdx.x >> 6);
  if (wid >= NN) return;
  int lane = threadIdx.x & 63;
  int grp = lane >> 4;          // 0..3: edge group (stride-4 edge walk)
  int d0 = (lane & 15) << 2;    // 4 dims owned per lane
  const unsigned char* __restrict__ xb = x + d0;
  int beg = rp[wid], end = rp[wid + 1];
  float a0 = 0.f, a1 = 0.f, a2 = 0.f, a3 = 0.f;
  float b0 = 0.f, b1 = 0.f, b2 = 0.f, b3 = 0.f;
  int j = beg + grp;
  // main: 4 edges per group per iter (16 edges/wave); cv[j] is 16-lane-uniform
  // -> single broadcast request; gather is 4B/lane = 64B/row segment.
  for (; j + 12 < end; j += 16) {
    int2 p0 = cv[j];
    int2 p1 = cv[j + 4];
    int2 p2 = cv[j + 8];
    int2 p3 = cv[j + 12];
    unsigned int h0 = *(const unsigned int*)(xb + ((size_t)p0.x << 6));
    unsigned int h1 = *(const unsigned int*)(xb + ((size_t)p1.x << 6));
    unsigned int h2 = *(const unsigned int*)(xb + ((size_t)p2.x << 6));
    unsigned int h3 = *(const unsigned int*)(xb + ((size_t)p3.x << 6));
    float v0 = __int_as_float(p0.y);
    float v1 = __int_as_float(p1.y);
    float v2 = __int_as_float(p2.y);
    float v3 = __int_as_float(p3.y);
    v2f f;
    f = __builtin_amdgcn_cvt_pk_f32_fp8(h0, false); a0 += v0 * f.x; a1 += v0 * f.y;
    f = __builtin_amdgcn_cvt_pk_f32_fp8(h0, true);  a2 += v0 * f.x; a3 += v0 * f.y;
    f = __builtin_amdgcn_cvt_pk_f32_fp8(h1, false); b0 += v1 * f.x; b1 += v1 * f.y;
    f = __builtin_amdgcn_cvt_pk_f32_fp8(h1, true);  b2 += v1 * f.x; b3 += v1 * f.y;
    f = __builtin_amdgcn_cvt_pk_f32_fp8(h2, false); a0 += v2 * f.x; a1 += v2 * f.y;
    f = __builtin_amdgcn_cvt_pk_f32_fp8(h2, true);  a2 += v2 * f.x; a3 += v2 * f.y;
    f = __builtin_amdgcn_cvt_pk_f32_fp8(h3, false); b0 += v3 * f.x; b1 += v3 * f.y;
    f = __builtin_amdgcn_cvt_pk_f32_fp8(h3, true);  b2 += v3 * f.x; b3 += v3 * f.y;
  }
  for (; j < end; j += 4) {  // tail: <=3 iters per group
    int2 p = cv[j];
    unsigned int h = *(const unsigned int*)(xb + ((size_t)p.x << 6));
    float v = __int_as_float(p.y);
    v2f f;
    f = __builtin_amdgcn_cvt_pk_f32_fp8(h, false); a0 += v * f.x; a1 += v * f.y;
    f = __builtin_amdgcn_cvt_pk_f32_fp8(h, true);  a2 += v * f.x; a3 += v * f.y;
  }
  a0 += b0; a1 += b1; a2 += b2; a3 += b3;
  // reduce the 4 groups (epilogue only)
  a0 += __shfl_xor(a0, 16); a1 += __shfl_xor(a1, 16);
  a2 += __shfl_xor(a2, 16); a3 += __shfl_xor(a3, 16);
  a0 += __shfl_xor(a0, 32); a1 += __shfl_xor(a1, 32);
  a2 += __shfl_xor(a2, 32); a3 += __shfl_xor(a3, 32);
  if (lane < 16) {
    int o = (wid << 6) | d0;
    if (FINAL) {
      float4 t = *(const float4*)&acc[o];
      t.x = (t.x + a0) * 0.25f;
      t.y = (t.y + a1) * 0.25f;
      t.z = (t.z + a2) * 0.25f;
      t.w = (t.w + a3) * 0.25f;
      *(float4*)&acc[o] = t;
    } else {
      *(unsigned int*)&y[o] = pk_fp8x4(a0, a1, a2, a3);
      float4 t = *(const float4*)&acc[o];
      t.x += a0; t.y += a1; t.z += a2; t.w += a3;
      *(float4*)&acc[o] = t;
    }
  }
}

extern "C" void kernel_launch(void* const* d_in, const int* in_sizes, int n_in,
                              void* d_out, int out_size, void* d_ws, size_t ws_size,
                              hipStream_t stream) {
  const int*   edge_row = (const int*)d_in[0];
  const int*   edge_col = (const int*)d_in[1];
  const float* edge_val = (const float*)d_in[2];
  const float* user_emb = (const float*)d_in[3];
  const float* item_id  = (const float*)d_in[4];
  const float* brand    = (const float*)d_in[5];
  const float* content  = (const float*)d_in[6];
  const float* W        = (const float*)d_in[7];
  const float* bias     = (const float*)d_in[8];
  float* out = (float*)d_out;

  char* ws = (char*)d_ws;
  size_t off = 0;
  auto alloc = [&](size_t bytes) -> void* {
    void* p = ws + off;
    off += (bytes + 255) & ~(size_t)255;
    return p;
  };
  unsigned char* x8_0 = (unsigned char*)alloc((size_t)NN * 64);  // 9.66 MB
  unsigned char* x8_1 = (unsigned char*)alloc((size_t)NN * 64);  // 9.66 MB
  int2*   cvtmp = (int2*)alloc((size_t)NE * 8);                  // 38.4 MB
  int2*   cv    = (int2*)alloc((size_t)NE * 8);                  // 38.4 MB
  int*    rp    = (int*)alloc((size_t)(NN + 1) * 4);
  int*    bcnt  = (int*)alloc((NBK + 1) * 4);
  int*    bstart= (int*)alloc((NBK + 1) * 4);
  int*    gfill = (int*)alloc((NBK + 1) * 4);
  if (off > ws_size) return;

  // --- build CSR via two-level counting sort ---
  // bcnt/bstart/gfill are contiguous in the workspace: one memset covers all
  // (bstart is fully overwritten by bucket_scan before use).
  hipMemsetAsync(bcnt, 0, (size_t)((char*)gfill - (char*)bcnt) + (NBK + 1) * 4,
                 stream);
  const int histBlocks = (NE + 256 * HIST_EPT - 1) / (256 * HIST_EPT);
  bucket_hist<<<histBlocks, 256, 0, stream>>>(edge_row, bcnt);
  bucket_scan<<<1, 256, 0, stream>>>(bcnt, bstart, rp);
  const int scBlocks = (NE + 256 * SC_EPT - 1) / (256 * SC_EPT);
  bucket_scatter<<<scBlocks, 256, 0, stream>>>(edge_row, edge_col, edge_val,
                                               bstart, gfill, cvtmp);
  csr_finalize<<<NBK, 256, 0, stream>>>(bstart, cvtmp, rp, cv);

  // --- ego assembly, acc seeding, fp8 conversion, passthrough (fused) ---
  fusion_kernel<<<(NI + 63) / 64, 256, 0, stream>>>(item_id, content, W, bias,
                                                    x8_0, out);
  const int seedTot = UN + BN + IEL;  // 9,664,000 floats
  seed_kernel<<<(seedTot / 4 + 255) / 256, 256, 0, stream>>>(user_emb, brand,
                                                             item_id, x8_0, out);

  // --- 3 propagation layers ---
  const int spmmGrid = (NN + 3) / 4;
  spmm_kernel<false><<<spmmGrid, 256, 0, stream>>>(rp, cv, x8_0, x8_1, out);
  spmm_kernel<false><<<spmmGrid, 256, 0, stream>>>(rp, cv, x8_1, x8_0, out);
  spmm_kernel<true><<<spmmGrid, 256, 0, stream>>>(rp, cv, x8_0, x8_1, out);
}